// Round 7
// baseline (137.774 us; speedup 1.0000x reference)
//
#include <hip/hip_runtime.h>
#include <math.h>

typedef __attribute__((ext_vector_type(8))) _Float16 half8;
typedef __attribute__((ext_vector_type(4))) _Float16 half4;
typedef __attribute__((ext_vector_type(4))) float    f32x4;

#define TSTEPS 28
#define IDIM   28
#define HDIM   128
#define NKC    5       // K chunks of 32: 160 = 128 (h) + 28 (x) + bias(1) + 3 pad
#define CDIM   10

#if __has_builtin(__builtin_amdgcn_exp2f)
#define EXP2F(x) __builtin_amdgcn_exp2f(x)
#else
#define EXP2F(x) exp2f(x)
#endif
#if __has_builtin(__builtin_amdgcn_rcpf)
#define RCPF(x) __builtin_amdgcn_rcpf(x)
#else
#define RCPF(x) (1.0f / (x))
#endif

#define NLOG2E (-1.44269504f)
#define P2LOG2E (2.88539008f)

// P[kc][t][w][lane][j] (f16): B-fragment order for mfma_f32_16x16x32_f16.
// Activation scales folded (i,f,o x -log2e; g x 2log2e). Bias row at k=156
// (pairs with constant 1.0 in A column 156). k=157..159 zero.
__global__ __launch_bounds__(256) void pack_w(const float* __restrict__ Wih,
                                              const float* __restrict__ Whh,
                                              const float* __restrict__ bih,
                                              const float* __restrict__ bhh,
                                              _Float16* __restrict__ P) {
    int e = blockIdx.x * 256 + threadIdx.x;      // 5*4*8*64*8 = 81920
    if (e >= NKC * 4 * 8 * 64 * 8) return;
    int j  = e & 7;
    int ln = (e >> 3) & 63;
    int w  = (e >> 9) & 7;
    int t  = (e >> 12) & 3;
    int kc = e >> 14;
    int k  = kc * 32 + ((ln >> 4) << 3) + j;
    int u  = w * 16 + (ln & 15);
    int g  = t * HDIM + u;
    float v = 0.f;
    if (k < HDIM)                   v = Whh[g * HDIM + k];
    else if (k < HDIM + IDIM)       v = Wih[g * IDIM + (k - HDIM)];
    else if (k == HDIM + IDIM)      v = bih[g] + bhh[g];   // bias row
    float sc = (t == 2) ? P2LOG2E : NLOG2E;
    P[e] = (_Float16)(v * sc);
}

__global__ __launch_bounds__(1024, 4) void lstm_kernel(
    const float* __restrict__ x,          // [B][28][28] fp32
    const _Float16* __restrict__ P,       // packed weights, 160 KB
    const float* __restrict__ Wfc,        // [10][128]
    const float* __restrict__ b_fc,       // [10]
    float* __restrict__ out)              // [B][10]
{
    // A-fragments: frag[tile][buf][kc][slot][j]; slot == reading lane
    __shared__ __align__(16) _Float16 frag[2][2][NKC][64][8];  // 20 KB
    __shared__ __align__(16) _Float16 Plds[4][8][64][8];       // 32 KB (kc=4 B-frags)
    __shared__ __align__(16) float hplain[32][HDIM + 4];       // 16.5 KB

    const int tid  = threadIdx.x;
    const int l    = tid & 63;
    const int w    = tid >> 6;                 // wave 0..15
    const int w7   = w & 7;                    // unit group
    const int hsel = w >> 3;                   // 0: tile0 (rows 0-15), 1: tile1
    const int b0   = blockIdx.x * 32;
    const int u    = w7 * 16 + (l & 15);

    // ---- stage B-frags for kc=4 into LDS (2048 float4) ----
    {
        const float4* P4 = (const float4*)P;
        float4* dst = (float4*)Plds;
        #pragma unroll
        for (int q = 0; q < 2; ++q)
            dst[tid + q * 1024] = P4[8192 + tid + q * 1024];
    }
    // ---- resident B-frags for kc=0..3 (AGPRs); same for both halves ----
    half8 breg[4][4];
    {
        const half8* Pp = (const half8*)P;
        #pragma unroll
        for (int kc = 0; kc < 4; ++kc)
            #pragma unroll
            for (int t4 = 0; t4 < 4; ++t4)
                breg[t4][kc] = Pp[((kc * 4 + t4) * 8 + w7) * 64 + l];
    }

    // ---- init LDS: zero h chunks of buf0 (both tiles); bias-1.0 column ----
    if (tid < 512) {
        float4 z = {0.f, 0.f, 0.f, 0.f};
        int tile = tid >> 8, q = tid & 255;
        ((float4*)&frag[tile][0][0][0][0])[q] = z;
    }
    if (tid < 64) {   // k=156 -> 1.0, k=157..159 -> 0, all tile/buf
        int tb = tid >> 4, i = tid & 15;
        half4 onev = {(_Float16)1.f, (_Float16)0.f, (_Float16)0.f, (_Float16)0.f};
        *(half4*)&frag[tb >> 1][tb & 1][4][48 + i][4] = onev;
    }
    // ---- stage x_0 for both tiles ----
    if (tid < 224) {
        int xr0 = tid / 7, xg0 = tid % 7;
        float4 xv = ((const float4*)(x + ((size_t)(b0 + xr0) * TSTEPS + 0) * IDIM))[xg0];
        half4 hv = {(_Float16)xv.x, (_Float16)xv.y, (_Float16)xv.z, (_Float16)xv.w};
        *(half4*)&frag[xr0 >> 4][0][4][(xr0 & 15) + 16 * (xg0 >> 1)][(xg0 & 1) * 4] = hv;
    }

    // x loader groups: T1-x by tid<112 (half0 waves 0-1); T0-x by tid in [512,624)
    const bool isL1 = (tid < 112);
    const bool isL0 = (tid >= 512 && tid < 624);
    const int  lx   = isL0 ? (tid - 512) : tid;   // 0..111 for loaders
    const int  xr   = lx / 7, xg = lx % 7;

    f32x4 acc[4];
    float cst[4] = {0.f, 0.f, 0.f, 0.f};
    half4 xh;
    const int kc_h = w7 >> 1;
    const int quad = (2 * w7 + ((l >> 3) & 1)) & 3;
    const int jh   = l & 7;

    auto mfma_tile = [&](int tile, int buf) {
        #pragma unroll
        for (int t4 = 0; t4 < 4; ++t4) { f32x4 z = {0.f, 0.f, 0.f, 0.f}; acc[t4] = z; }
        #pragma unroll
        for (int kc = 0; kc < NKC; ++kc) {
            half8 a = *(const half8*)&frag[tile][buf][kc][l][0];
            if (kc < 4) {
                acc[0] = __builtin_amdgcn_mfma_f32_16x16x32_f16(a, breg[0][kc], acc[0], 0, 0, 0);
                acc[1] = __builtin_amdgcn_mfma_f32_16x16x32_f16(a, breg[1][kc], acc[1], 0, 0, 0);
                acc[2] = __builtin_amdgcn_mfma_f32_16x16x32_f16(a, breg[2][kc], acc[2], 0, 0, 0);
                acc[3] = __builtin_amdgcn_mfma_f32_16x16x32_f16(a, breg[3][kc], acc[3], 0, 0, 0);
            } else {
                #pragma unroll
                for (int t4 = 0; t4 < 4; ++t4) {
                    half8 b = *(const half8*)&Plds[t4][w7][l][0];
                    acc[t4] = __builtin_amdgcn_mfma_f32_16x16x32_f16(a, b, acc[t4], 0, 0, 0);
                }
            }
        }
    };
    auto act_tile = [&](int tile, int nb, bool last) {
        #pragma unroll
        for (int r = 0; r < 4; ++r) {
            float Ei = EXP2F(acc[0][r]);     // e^{-i}
            float Ef = EXP2F(acc[1][r]);     // e^{-f}
            float Eg = EXP2F(acc[2][r]);     // e^{2g}
            float Eo = EXP2F(acc[3][r]);     // e^{-o}
            float Di = 1.f + Ei, Df = 1.f + Ef, Dg = 1.f + Eg, Do = 1.f + Eo;
            float Rif = RCPF(Di * Df);
            float Rgo = RCPF(Dg * Do);
            float is = Rif * Df, fs = Rif * Di;
            float gt = 1.f - 2.f * (Rgo * Do);
            float os = Rgo * Dg;
            float c  = fs * cst[r] + is * gt;
            cst[r] = c;
            float tc = 1.f - 2.f * RCPF(1.f + EXP2F(c * P2LOG2E));
            float h  = os * tc;
            int m = ((l >> 4) << 2) + r;
            frag[tile][nb][kc_h][m + 16 * quad][jh] = (_Float16)h;
            if (last) hplain[tile * 16 + m][u] = h;
        }
    };

    __syncthreads();

    // schedule per step t (cb = t&1, nb = cb^1):
    //  sub A: half0 MFMA(T0,t) [+T1-x store] | half1 act(T1,t-1) [+T0-x load x_{t+1}]
    //  sub B: half0 act(T0,t)  [+T1-x load]  | half1 MFMA(T1,t)  [+T0-x store x_{t+1}]
    auto step = [&](int t, int cb) {
        const int nb = cb ^ 1;
        if (hsel == 0) {
            mfma_tile(0, cb);
            if (isL1 && t > 0)
                *(half4*)&frag[1][cb][4][xr + 16 * (xg >> 1)][(xg & 1) * 4] = xh;
        } else {
            if (t > 0) act_tile(1, cb, false);
            if (isL0 && t + 1 < TSTEPS) {
                float4 xv = ((const float4*)(x + ((size_t)(b0 + xr) * TSTEPS + (t + 1)) * IDIM))[xg];
                half4 hv = {(_Float16)xv.x, (_Float16)xv.y, (_Float16)xv.z, (_Float16)xv.w};
                xh = hv;
            }
        }
        __syncthreads();
        if (hsel == 0) {
            act_tile(0, nb, t == TSTEPS - 1);
            if (isL1 && t + 1 < TSTEPS) {
                float4 xv = ((const float4*)(x + ((size_t)(b0 + 16 + xr) * TSTEPS + (t + 1)) * IDIM))[xg];
                half4 hv = {(_Float16)xv.x, (_Float16)xv.y, (_Float16)xv.z, (_Float16)xv.w};
                xh = hv;
            }
        } else {
            mfma_tile(1, cb);
            if (isL0 && t + 1 < TSTEPS)
                *(half4*)&frag[0][nb][4][xr + 16 * (xg >> 1)][(xg & 1) * 4] = xh;
        }
        __syncthreads();
    };

    for (int t = 0; t < TSTEPS; t += 2) {
        step(t, 0);
        step(t + 1, 1);
    }
    // epilogue: T1's last activation (step 27)
    if (hsel == 1) act_tile(1, 0, true);
    __syncthreads();

    // ---- FC + ReLU epilogue: 32 rows x 10 classes ----
    if (tid < 32 * CDIM) {
        int row = tid / CDIM, c = tid % CDIM;
        const float4* hv = (const float4*)&hplain[row][0];
        const float4* wf = (const float4*)(Wfc + c * HDIM);
        float s = b_fc[c];
        #pragma unroll
        for (int q = 0; q < 32; ++q) {
            float4 a = hv[q], b = wf[q];
            s += a.x * b.x + a.y * b.y + a.z * b.z + a.w * b.w;
        }
        out[(size_t)(b0 + row) * CDIM + c] = fmaxf(s, 0.f);
    }
}

extern "C" void kernel_launch(void* const* d_in, const int* in_sizes, int n_in,
                              void* d_out, int out_size, void* d_ws, size_t ws_size,
                              hipStream_t stream) {
    const float* x   = (const float*)d_in[0];
    const float* Wih = (const float*)d_in[1];
    const float* Whh = (const float*)d_in[2];
    const float* bih = (const float*)d_in[3];
    const float* bhh = (const float*)d_in[4];
    const float* Wfc = (const float*)d_in[5];
    const float* bfc = (const float*)d_in[6];
    float* out = (float*)d_out;
    _Float16* P = (_Float16*)d_ws;     // 160 KB packed weights

    hipLaunchKernelGGL(pack_w, dim3(320), dim3(256), 0, stream, Wih, Whh, bih, bhh, P);
    hipLaunchKernelGGL(lstm_kernel, dim3(8192 / 32), dim3(1024), 0, stream,
                       x, P, Wfc, bfc, out);
}

// Round 8
// 125.673 us; speedup vs baseline: 1.0963x; 1.0963x over previous
//
#include <hip/hip_runtime.h>
#include <math.h>

typedef __attribute__((ext_vector_type(8))) _Float16 half8;
typedef __attribute__((ext_vector_type(4))) _Float16 half4;
typedef __attribute__((ext_vector_type(4))) float    f32x4;

#define TSTEPS 28
#define IDIM   28
#define HDIM   128
#define NKC    5       // K chunks of 32: 160 = 128 (h) + 28 (x) + bias(1) + 3 pad
#define TILE_B 16
#define CDIM   10

#if __has_builtin(__builtin_amdgcn_exp2f)
#define EXP2F(x) __builtin_amdgcn_exp2f(x)
#else
#define EXP2F(x) exp2f(x)
#endif
#if __has_builtin(__builtin_amdgcn_rcpf)
#define RCPF(x) __builtin_amdgcn_rcpf(x)
#else
#define RCPF(x) (1.0f / (x))
#endif

#define NLOG2E (-1.44269504f)
#define P2LOG2E (2.88539008f)

// P[kc][t][w][lane][j] (f16): B-fragment order for mfma_f32_16x16x32_f16.
// Activation scales folded (i,f,o x -log2e; g x 2log2e). Bias row at k=156
// (pairs with constant 1.0 in A column 156). k=157..159 zero.
__global__ __launch_bounds__(256) void pack_w(const float* __restrict__ Wih,
                                              const float* __restrict__ Whh,
                                              const float* __restrict__ bih,
                                              const float* __restrict__ bhh,
                                              _Float16* __restrict__ P) {
    int e = blockIdx.x * 256 + threadIdx.x;      // 5*4*8*64*8 = 81920
    if (e >= NKC * 4 * 8 * 64 * 8) return;
    int j  = e & 7;
    int ln = (e >> 3) & 63;
    int w  = (e >> 9) & 7;
    int t  = (e >> 12) & 3;
    int kc = e >> 14;
    int k  = kc * 32 + ((ln >> 4) << 3) + j;
    int u  = w * 16 + (ln & 15);
    int g  = t * HDIM + u;
    float v = 0.f;
    if (k < HDIM)                   v = Whh[g * HDIM + k];
    else if (k < HDIM + IDIM)       v = Wih[g * IDIM + (k - HDIM)];
    else if (k == HDIM + IDIM)      v = bih[g] + bhh[g];   // bias row
    float sc = (t == 2) ? P2LOG2E : NLOG2E;
    P[e] = (_Float16)(v * sc);
}

__global__ __launch_bounds__(512, 2) void lstm_kernel(
    const float* __restrict__ x,          // [B][28][28] fp32
    const _Float16* __restrict__ P,       // packed weights, 160 KB
    const float* __restrict__ Wfc,        // [10][128]
    const float* __restrict__ b_fc,       // [10]
    float* __restrict__ out)              // [B][10]
{
    // Double-buffered A-fragments: frag[buf][kc][slot][j]; slot == reading lane
    __shared__ __align__(16) _Float16 frag[2][NKC][64][8];     // 10 KB
    __shared__ __align__(16) _Float16 Plds[4][8][64][8];       // 32 KB (kc=4 B-frags)
    __shared__ __align__(16) float hplain[TILE_B][HDIM + 4];   // 8.25 KB

    const int tid = threadIdx.x;
    const int l   = tid & 63;
    const int w   = tid >> 6;                  // wave 0..7
    const int b0  = blockIdx.x * TILE_B;

    // ---- stage B-frags for kc=4 into LDS (2048 float4) ----
    {
        const float4* P4 = (const float4*)P;
        float4* dst = (float4*)Plds;
        #pragma unroll
        for (int q = 0; q < 4; ++q)
            dst[tid + q * 512] = P4[8192 + tid + q * 512];
    }
    // ---- resident B-frags for kc=0..3 (parked in AGPRs) ----
    half8 breg[4][4];
    {
        const half8* Pp = (const half8*)P;
        #pragma unroll
        for (int kc = 0; kc < 4; ++kc)
            #pragma unroll
            for (int t4 = 0; t4 < 4; ++t4)
                breg[t4][kc] = Pp[((kc * 4 + t4) * 8 + w) * 64 + l];
    }

    // ---- init LDS: zero h chunks of buf0; bias-1.0 column in BOTH buffers ----
    if (tid < 256) {                           // chunks 0..3 of buf0 = 256 float4
        float4 z = {0.f, 0.f, 0.f, 0.f};
        ((float4*)&frag[0][0][0][0])[tid] = z;
    }
    if (tid < 32) {   // k=156 -> 1.0, k=157..159 -> 0 (slots 48..63, j=4..7)
        int b = tid >> 4, i = tid & 15;
        half4 onev = {(_Float16)1.f, (_Float16)0.f, (_Float16)0.f, (_Float16)0.f};
        *(half4*)&frag[b][4][48 + i][4] = onev;
    }
    // ---- stage x_0 into buf0 chunk 4 ----
    const int xrow = tid / 7, xg = tid % 7;
    if (tid < 112) {
        float4 xv = ((const float4*)(x + ((size_t)(b0 + xrow) * TSTEPS + 0) * IDIM))[xg];
        half4 hv = {(_Float16)xv.x, (_Float16)xv.y, (_Float16)xv.z, (_Float16)xv.w};
        *(half4*)&frag[0][4][xrow + 16 * (xg >> 1)][(xg & 1) * 4] = hv;
    }

    float cst[4] = {0.f, 0.f, 0.f, 0.f};
    const int u    = w * 16 + (l & 15);
    const int kc_h = w >> 1;                       // u>>5 (wave-uniform)
    const int quad = (2 * w + ((l >> 3) & 1)) & 3; // (u>>3)&3
    const int jh   = l & 7;                        // u&7

    __syncthreads();

    // anti-phase the second co-resident block on each CU (~1600 cyc ~ half step)
#if __has_builtin(__builtin_amdgcn_s_sleep)
    if (blockIdx.x & 256) __builtin_amdgcn_s_sleep(25);
#endif

    // one step: read A-frags from cur, write h/x_{t+1} into nxt, ONE barrier
    auto step = [&](int t, const _Float16 (*cur)[64][8], _Float16 (*nxt)[64][8]) {
        const bool last = (t == TSTEPS - 1);
        // x_{t+1}: issue global load now; latency hides behind MFMA+act
        float4 xv;
        const bool doload = (t + 1 < TSTEPS) && (tid < 112);
        if (doload)
            xv = ((const float4*)(x + ((size_t)(b0 + xrow) * TSTEPS + (t + 1)) * IDIM))[xg];

        // preload all 5 A-fragments (5 x ds_read_b128)
        half8 a[NKC];
        #pragma unroll
        for (int kc = 0; kc < NKC; ++kc)
            a[kc] = *(const half8*)&cur[kc][l][0];

        // t4-major: acc[0] (i-gate) completes first so its exp can start early
        f32x4 acc[4];
        #pragma unroll
        for (int t4 = 0; t4 < 4; ++t4) {
            f32x4 z = {0.f, 0.f, 0.f, 0.f};
            acc[t4] = z;
            #pragma unroll
            for (int kc = 0; kc < 4; ++kc)
                acc[t4] = __builtin_amdgcn_mfma_f32_16x16x32_f16(a[kc], breg[t4][kc], acc[t4], 0, 0, 0);
            half8 b = *(const half8*)&Plds[t4][w][l][0];
            acc[t4] = __builtin_amdgcn_mfma_f32_16x16x32_f16(a[4], b, acc[t4], 0, 0, 0);
        }

        // activations (scales pre-folded: i,f,o hold -x*log2e; g holds 2x*log2e)
        #pragma unroll
        for (int r = 0; r < 4; ++r) {
            float Ei = EXP2F(acc[0][r]);     // e^{-i}
            float Ef = EXP2F(acc[1][r]);     // e^{-f}
            float Eg = EXP2F(acc[2][r]);     // e^{2g}
            float Eo = EXP2F(acc[3][r]);     // e^{-o}
            float Di = 1.f + Ei, Df = 1.f + Ef, Dg = 1.f + Eg, Do = 1.f + Eo;
            float Rif = RCPF(Di * Df);
            float Rgo = RCPF(Dg * Do);
            float is = Rif * Df, fs = Rif * Di;
            float gt = 1.f - 2.f * (Rgo * Do);
            float os = Rgo * Dg;
            float c  = fs * cst[r] + is * gt;
            cst[r] = c;
            float tc = 1.f - 2.f * RCPF(1.f + EXP2F(c * P2LOG2E));
            float h  = os * tc;
            int m = ((l >> 4) << 2) + r;
            nxt[kc_h][m + 16 * quad][jh] = (_Float16)h;
            if (last) hplain[m][u] = h;
        }
        // commit x_{t+1} into nxt chunk 4
        if (doload) {
            half4 hv = {(_Float16)xv.x, (_Float16)xv.y, (_Float16)xv.z, (_Float16)xv.w};
            *(half4*)&nxt[4][xrow + 16 * (xg >> 1)][(xg & 1) * 4] = hv;
        }
        __syncthreads();
    };

    for (int tt = 0; tt < TSTEPS; tt += 2) {
        step(tt,     frag[0], frag[1]);
        step(tt + 1, frag[1], frag[0]);
    }

    // ---- FC + ReLU epilogue ----
    if (tid < TILE_B * CDIM) {
        int row = tid / CDIM, c = tid % CDIM;
        const float4* hv = (const float4*)&hplain[row][0];
        const float4* wf = (const float4*)(Wfc + c * HDIM);
        float s = b_fc[c];
        #pragma unroll
        for (int q = 0; q < 32; ++q) {
            float4 a4 = hv[q], b4 = wf[q];
            s += a4.x * b4.x + a4.y * b4.y + a4.z * b4.z + a4.w * b4.w;
        }
        out[(size_t)(b0 + row) * CDIM + c] = fmaxf(s, 0.f);
    }
}

extern "C" void kernel_launch(void* const* d_in, const int* in_sizes, int n_in,
                              void* d_out, int out_size, void* d_ws, size_t ws_size,
                              hipStream_t stream) {
    const float* x   = (const float*)d_in[0];
    const float* Wih = (const float*)d_in[1];
    const float* Whh = (const float*)d_in[2];
    const float* bih = (const float*)d_in[3];
    const float* bhh = (const float*)d_in[4];
    const float* Wfc = (const float*)d_in[5];
    const float* bfc = (const float*)d_in[6];
    float* out = (float*)d_out;
    _Float16* P = (_Float16*)d_ws;     // 160 KB packed weights

    hipLaunchKernelGGL(pack_w, dim3(320), dim3(256), 0, stream, Wih, Whh, bih, bhh, P);
    hipLaunchKernelGGL(lstm_kernel, dim3(8192 / TILE_B), dim3(512), 0, stream,
                       x, P, Wfc, bfc, out);
}